// Round 11
// baseline (123.745 us; speedup 1.0000x reference)
//
#include <hip/hip_runtime.h>
#include <math.h>

// GCN link predictor, sparse-cone evaluation (round 13).
// Round-12 post-mortem: dur 122.0; k_fused fell BELOW the harness's 43us
// poison fills (<42us) - prediction held. Residual kernel model (~35us):
// ramp 4 + 3 scans x2.5 + 5 barriers x2 + agg 2.5 + h1/B5 4 + tail 3.
// This round:
//  - deg for F1 nodes counted inside P2 (d-in-lbm already tested; ~550
//    atomics free). P2 also records bmOut[s] for s not in F1. P3 now tests
//    only the OUTER set (exact split: outer and F1 disjoint, union = need).
//    bmNd eliminated.
//  - barriers 5->4: h1 GEMM (34 rows, dense, pipelineable - NOT the r9
//    latency-bound gather) moves into block 0 before the tail; blocks != 0
//    arrive once after agg and exit.
//  - h1 kept in LDS (cap 256 rows, global fallback): tail reads become LDS
//    hits instead of LLC round trips.
//
// Phases (one plain launch, 4 fenceless flag barriers):
//  P1  scan dst: e1 edges; register F1                        -- B1 --
//  P2  bmF1->LDS; scan dst: e2 edges + deg[d in F1]++ +
//      bmOut[s not in F1]                                     -- B2 --
//  P3  bmOut->LDS; scan dst: deg[d]++ if outer                -- B3 --
//  P4  edge-parallel agg incl. self-loop virtual edges        -- B4 --
//      (blocks != 0 arrive & exit; block 0 waits)
//  P5  block 0: h1 = relu(agg1e @ W1 + b1) into LDS   (syncthreads)
//  P6  block 0: layer-2 agg + @W2+b2, relu, fc, sigmoid

#define CH 64
#define E1CAP 4096
#define F1CAP (E1CAP + 2)
#define E2CAP 131072
#define GRID 256
#define BLK 512
#define NWAVE (BLK / 64)
#define BMCAP 3200
#define HCAP 256
#define SPIN_MAX (1 << 20)

struct Params {
    const float* x;
    const int* src; const int* dst; const int* np_;
    const float* W1; const float* b1;
    const float* W2; const float* b2;
    const float* fcW; const float* fcb;
    int* bar;          // [16*b] = block b flag (64B stride), monotone
    int* ctrl;         // [0]=cnt_e1 [1]=cnt_e2 [2]=nf1
    int* deg;
    unsigned* bmF1; unsigned* bmOut;
    int* pos1; long long* e1sd; int* F1;
    long long* e2sd; float* h1g; float* agg1e;
    float* out;
    int E; int N; int bmN;
};

__device__ __forceinline__ float dinv_of(int degv) {
    return rsqrtf((float)(degv + 1));
}

__device__ __forceinline__ void st_agent(int* p, int v) {
    __hip_atomic_store(p, v, __ATOMIC_RELAXED, __HIP_MEMORY_SCOPE_AGENT);
}
__device__ __forceinline__ void st_agent_f(float* p, float v) {
    __hip_atomic_store(p, v, __ATOMIC_RELAXED, __HIP_MEMORY_SCOPE_AGENT);
}
__device__ __forceinline__ void st_agent64(long long* p, long long v) {
    __hip_atomic_store(p, v, __ATOMIC_RELAXED, __HIP_MEMORY_SCOPE_AGENT);
}
__device__ __forceinline__ int ld_agent(const int* p) {
    return __hip_atomic_load((int*)p, __ATOMIC_RELAXED, __HIP_MEMORY_SCOPE_AGENT);
}
__device__ __forceinline__ unsigned ld_agent_u(const unsigned* p) {
    return __hip_atomic_load((unsigned*)p, __ATOMIC_RELAXED, __HIP_MEMORY_SCOPE_AGENT);
}
__device__ __forceinline__ long long ld_agent64(const long long* p) {
    return __hip_atomic_load((long long*)p, __ATOMIC_RELAXED, __HIP_MEMORY_SCOPE_AGENT);
}
__device__ __forceinline__ float ld_agent_f(const float* p) {
    return __hip_atomic_load((float*)p, __ATOMIC_RELAXED, __HIP_MEMORY_SCOPE_AGENT);
}

// Fenceless barrier (uncached-mutable discipline; R8-proven).
__device__ __forceinline__ void gbar_arrive(int* bar, int phase) {
    __syncthreads();
    if (threadIdx.x == 0) {
        asm volatile("" ::: "memory");
        st_agent(&bar[blockIdx.x << 4], phase);
    }
}
__device__ __forceinline__ void gbar_wait(int* bar, int phase) {
    if (threadIdx.x < 64) {
        const int l = threadIdx.x;
        for (int it = 0; ; ++it) {
            int a = ld_agent(&bar[l << 4]);
            int b = ld_agent(&bar[(l + 64) << 4]);
            int c = ld_agent(&bar[(l + 128) << 4]);
            int d = ld_agent(&bar[(l + 192) << 4]);
            if (__all(min(min(a, b), min(c, d)) >= phase) || it > SPIN_MAX) break;
            __builtin_amdgcn_s_sleep(1);
        }
    }
    __syncthreads();
}
__device__ __forceinline__ void gbar(int* bar, int phase) {
    gbar_arrive(bar, phase);
    gbar_wait(bar, phase);
}

__device__ __forceinline__ void reg_node(int u, unsigned* bmF1,
                                         int* ctrl, int* F1, int* pos1) {
    unsigned bit = 1u << (u & 31);
    unsigned old = atomicOr(&bmF1[u >> 5], bit);
    if (!(old & bit)) {
        int i = atomicAdd(&ctrl[2], 1);
        st_agent(&F1[i], u);
        st_agent(&pos1[u], i);
    }
}

__device__ __forceinline__ long long pack_sd(int s, int d) {
    return ((long long)(unsigned)d << 32) | (unsigned)s;
}

// P1: batched scan; e1 collection + F1 registration.
__device__ __forceinline__ void phase_e1f1(int gid, int gsz,
                                           const int* __restrict__ src,
                                           const int* __restrict__ dst, int E,
                                           int p0, int p1, int* ctrl,
                                           long long* e1sd, unsigned* bmF1,
                                           int* F1, int* pos1) {
    if (gid == 0) {
        reg_node(p0, bmF1, ctrl, F1, pos1);
        if (p1 != p0) reg_node(p1, bmF1, ctrl, F1, pos1);
    }
    const int nvec = E >> 2;
    const int4* dst4 = (const int4*)dst;
    for (int base = gid; base < nvec; base += gsz * 4) {
        int4 v[4];
#pragma unroll
        for (int t = 0; t < 4; t++) {
            int i = base + t * gsz;
            if (i < nvec) v[t] = dst4[i];
        }
#pragma unroll
        for (int t = 0; t < 4; t++) {
            int i = base + t * gsz;
            if (i >= nvec) continue;
            int ds[4] = {v[t].x, v[t].y, v[t].z, v[t].w};
#pragma unroll
            for (int k = 0; k < 4; k++) {
                int d = ds[k];
                if (d == p0 || d == p1) {
                    int s = src[i * 4 + k];
                    int idx = atomicAdd(&ctrl[0], 1);
                    if (idx < E1CAP) st_agent64(&e1sd[idx], pack_sd(s, d));
                    reg_node(s, bmF1, ctrl, F1, pos1);
                }
            }
        }
    }
    for (int e = (nvec << 2) + gid; e < E; e += gsz) {
        int d = dst[e];
        if (d == p0 || d == p1) {
            int s = src[e];
            int idx = atomicAdd(&ctrl[0], 1);
            if (idx < E1CAP) st_agent64(&e1sd[idx], pack_sd(s, d));
            reg_node(s, bmF1, ctrl, F1, pos1);
        }
    }
}

// P2: bmF1 -> LDS; scan: e2 collection + deg for F1 dsts + bmOut for outer
// srcs. deg[d] for d in F1 is EXACT here (every edge tested once grid-wide).
__device__ __forceinline__ void phase_e2deg(int tid, int gid, int gsz,
                                            const int* __restrict__ src,
                                            const int* __restrict__ dst, int E,
                                            const unsigned* __restrict__ bmF1,
                                            unsigned* bmOut, int* deg,
                                            int* ctrl, long long* e2sd,
                                            unsigned* lbm, int bmN) {
    const bool lds_ok = (bmN <= BMCAP);
    if (lds_ok)
        for (int i = tid; i < bmN; i += BLK) lbm[i] = ld_agent_u(&bmF1[i]);
    __syncthreads();
    const int nvec = E >> 2;
    const int4* dst4 = (const int4*)dst;
    for (int base = gid; base < nvec; base += gsz * 4) {
        int4 v[4];
#pragma unroll
        for (int t = 0; t < 4; t++) {
            int i = base + t * gsz;
            if (i < nvec) v[t] = dst4[i];
        }
#pragma unroll
        for (int t = 0; t < 4; t++) {
            int i = base + t * gsz;
            if (i >= nvec) continue;
            int ds[4] = {v[t].x, v[t].y, v[t].z, v[t].w};
#pragma unroll
            for (int k = 0; k < 4; k++) {
                int d = ds[k];
                unsigned word = lds_ok ? lbm[d >> 5] : ld_agent_u(&bmF1[d >> 5]);
                if ((word >> (d & 31)) & 1u) {
                    int s = src[i * 4 + k];
                    atomicAdd(&deg[d], 1);
                    unsigned sw = lds_ok ? lbm[s >> 5] : ld_agent_u(&bmF1[s >> 5]);
                    if (!((sw >> (s & 31)) & 1u))
                        atomicOr(&bmOut[s >> 5], 1u << (s & 31));
                    int idx = atomicAdd(&ctrl[1], 1);
                    if (idx < E2CAP) st_agent64(&e2sd[idx], pack_sd(s, d));
                }
            }
        }
    }
    for (int e = (nvec << 2) + gid; e < E; e += gsz) {
        int d = dst[e];
        unsigned word = lds_ok ? lbm[d >> 5] : ld_agent_u(&bmF1[d >> 5]);
        if ((word >> (d & 31)) & 1u) {
            int s = src[e];
            atomicAdd(&deg[d], 1);
            unsigned sw = lds_ok ? lbm[s >> 5] : ld_agent_u(&bmF1[s >> 5]);
            if (!((sw >> (s & 31)) & 1u))
                atomicOr(&bmOut[s >> 5], 1u << (s & 31));
            int idx = atomicAdd(&ctrl[1], 1);
            if (idx < E2CAP) st_agent64(&e2sd[idx], pack_sd(s, d));
        }
    }
}

// P3: bmOut -> LDS; deg for outer nodes (disjoint from F1 -> no dupes).
__device__ __forceinline__ void phase_degout(int tid, int gid, int gsz,
                                             const int* __restrict__ dst, int E,
                                             const unsigned* __restrict__ bmOut,
                                             int* deg, unsigned* lbm, int bmN) {
    const bool lds_ok = (bmN <= BMCAP);
    __syncthreads();                    // lbm reuse: P2 readers done
    if (lds_ok)
        for (int i = tid; i < bmN; i += BLK) lbm[i] = ld_agent_u(&bmOut[i]);
    __syncthreads();
    const int nvec = E >> 2;
    const int4* dst4 = (const int4*)dst;
    for (int base = gid; base < nvec; base += gsz * 4) {
        int4 v[4];
#pragma unroll
        for (int t = 0; t < 4; t++) {
            int i = base + t * gsz;
            if (i < nvec) v[t] = dst4[i];
        }
#pragma unroll
        for (int t = 0; t < 4; t++) {
            int i = base + t * gsz;
            if (i >= nvec) continue;
            int ds[4] = {v[t].x, v[t].y, v[t].z, v[t].w};
#pragma unroll
            for (int k = 0; k < 4; k++) {
                int d = ds[k];
                unsigned word = lds_ok ? lbm[d >> 5] : ld_agent_u(&bmOut[d >> 5]);
                if ((word >> (d & 31)) & 1u) atomicAdd(&deg[d], 1);
            }
        }
    }
    for (int e = (nvec << 2) + gid; e < E; e += gsz) {
        int d = dst[e];
        unsigned word = lds_ok ? lbm[d >> 5] : ld_agent_u(&bmOut[d >> 5]);
        if ((word >> (d & 31)) & 1u) atomicAdd(&deg[d], 1);
    }
}

// P4: edge-parallel aggregation incl. self-loop virtual edges (grid-wide:
// the scattered x-row gather needs full-chip TLP - r9 lesson).
__device__ __forceinline__ void phase_agg(int gid, int gsz,
                                          const float* __restrict__ x,
                                          const int* __restrict__ deg,
                                          const int* __restrict__ pos1,
                                          const int* __restrict__ ctrl,
                                          const long long* __restrict__ e2sd,
                                          const int* __restrict__ F1,
                                          float* __restrict__ agg1e) {
    int cnt2 = min(ld_agent(&ctrl[1]), E2CAP);
    int nf1  = min(ld_agent(&ctrl[2]), F1CAP);
    int total = (cnt2 + nf1) << 6;
    for (int idx = gid; idx < total; idx += gsz) {
        int e = idx >> 6, c = idx & 63;
        int row; float val;
        if (e < cnt2) {
            long long sd = ld_agent64(&e2sd[e]);
            int s = (int)(sd & 0xffffffffll), u = (int)(sd >> 32);
            float nrm = dinv_of(ld_agent(&deg[s])) * dinv_of(ld_agent(&deg[u]));
            row = ld_agent(&pos1[u]);
            val = nrm * x[(size_t)s * CH + c];
        } else {
            int i = e - cnt2;
            int u = ld_agent(&F1[i]);
            float du = dinv_of(ld_agent(&deg[u]));
            row = i;
            val = du * du * x[(size_t)u * CH + c];
        }
        atomicAdd(&agg1e[row * CH + c], val);
    }
}

__global__ __launch_bounds__(BLK, 1) void k_fused(Params p) {
    __shared__ unsigned lbm[BMCAP];       // 12.8 KB bitmap mirror
    __shared__ float h1l[HCAP][CH];       // 64 KB h1 (block-0 use)
    __shared__ float a[NWAVE][CH];
    __shared__ float a2p[NWAVE][CH];
    __shared__ float a2[2][CH];
    __shared__ float partial[2];
    const int gid = blockIdx.x * BLK + threadIdx.x;
    const int gsz = GRID * BLK;
    const int tid = threadIdx.x;

    phase_e1f1(gid, gsz, p.src, p.dst, p.E, p.np_[0], p.np_[1], p.ctrl,
               p.e1sd, p.bmF1, p.F1, p.pos1);
    gbar(p.bar, 1);
    phase_e2deg(tid, gid, gsz, p.src, p.dst, p.E, p.bmF1, p.bmOut, p.deg,
                p.ctrl, p.e2sd, lbm, p.bmN);
    gbar(p.bar, 2);
    phase_degout(tid, gid, gsz, p.dst, p.E, p.bmOut, p.deg, lbm, p.bmN);
    gbar(p.bar, 3);
    phase_agg(gid, gsz, p.x, p.deg, p.pos1, p.ctrl, p.e2sd, p.F1, p.agg1e);
    gbar_arrive(p.bar, 4);
    if (blockIdx.x != 0) return;          // blocks 1..255 done
    gbar_wait(p.bar, 4);

    // ---- P5 (block 0): h1 = relu(agg1e @ W1 + b1), rows into LDS ----
    const int nf1  = min(ld_agent(&p.ctrl[2]), F1CAP);
    const int cnt1 = min(ld_agent(&p.ctrl[0]), E1CAP);
    const bool h_lds = (nf1 <= HCAP);
    const int w = tid >> 6, j = tid & 63;
    for (int i = w; i < nf1; i += NWAVE) {
        a[w][j] = ld_agent_f(&p.agg1e[i * CH + j]);   // same-wave LDS RAW
        float sum = p.b1[j];
#pragma unroll
        for (int k = 0; k < CH; k++) sum += a[w][k] * p.W1[k * CH + j];
        float hv = fmaxf(sum, 0.f);
        if (h_lds) h1l[i][j] = hv; else p.h1g[i * CH + j] = hv;
    }
    __syncthreads();

    // ---- P6 (block 0): layer-2 agg (4 waves/endpoint) + head ----
    {
        int t = w >> 2, sub = w & 3;
        int pp = p.np_[t];
        float dp = dinv_of(ld_agent(&p.deg[pp]));
        int rp = ld_agent(&p.pos1[pp]);
        float acc = 0.f;
        if (sub == 0)
            acc = dp * dp * (h_lds ? h1l[rp][j] : p.h1g[rp * CH + j]);
        for (int e = sub; e < cnt1; e += 4) {
            long long sd = ld_agent64(&p.e1sd[e]);
            int s = (int)(sd & 0xffffffffll), d = (int)(sd >> 32);
            if (d == pp) {
                int rs = ld_agent(&p.pos1[s]);
                float hv = h_lds ? h1l[rs][j] : p.h1g[rs * CH + j];
                acc += dinv_of(ld_agent(&p.deg[s])) * dp * hv;
            }
        }
        a2p[w][j] = acc;
    }
    __syncthreads();
    if (tid < 128) {
        int t2 = tid >> 6;
        a2[t2][j] = a2p[t2 * 4][j] + a2p[t2 * 4 + 1][j] +
                    a2p[t2 * 4 + 2][j] + a2p[t2 * 4 + 3][j];
    }
    __syncthreads();
    if (tid < 128) {
        int t2 = tid >> 6;
        float sum = p.b2[j];
#pragma unroll
        for (int k = 0; k < CH; k++) sum += a2[t2][k] * p.W2[k * CH + j];
        float v = fmaxf(sum, 0.f);
        float pr = v * p.fcW[t2 * CH + j];
        for (int off = 32; off > 0; off >>= 1) pr += __shfl_down(pr, off);
        if (j == 0) partial[t2] = pr;
    }
    __syncthreads();
    if (tid == 0) {
        float z = partial[0] + partial[1] + p.fcb[0];
        ((float*)p.out)[0] = 1.f / (1.f + expf(-z));
    }
}

extern "C" void kernel_launch(void* const* d_in, const int* in_sizes, int n_in,
                              void* d_out, int out_size, void* d_ws, size_t ws_size,
                              hipStream_t stream) {
    const float* x   = (const float*)d_in[0];
    const int*   ei  = (const int*)d_in[1];
    const int*   np_ = (const int*)d_in[2];

    const int N = in_sizes[0] / CH;
    const int E = in_sizes[1] / 2;
    const int bmN = (N + 31) / 32;

    char* w = (char*)d_ws;
    size_t off = 0;
    auto alloc = [&](size_t bytes) {
        size_t o = off;
        off = (off + bytes + 255) & ~((size_t)255);
        return o;
    };
    // --- zeroed region (~1.5 MB, fill engine): bar + ctrl + bitmaps + deg
    //     + agg1e ---
    size_t o_bar  = alloc((size_t)GRID * 16 * 4);   // 64B-strided flags
    size_t o_ctrl = alloc(64);                      // cnt_e1, cnt_e2, nf1
    size_t o_bmF1 = alloc((size_t)bmN * 4);
    size_t o_bmOut= alloc((size_t)bmN * 4);
    size_t o_deg  = alloc((size_t)N * 4);
    size_t o_agg  = alloc((size_t)F1CAP * CH * 4);
    size_t zero_end = off;
    // --- uninitialized region ---
    size_t o_pos  = alloc((size_t)N * 4);
    size_t o_e1sd = alloc((size_t)E1CAP * 8);
    size_t o_F1   = alloc((size_t)F1CAP * 4);
    size_t o_e2sd = alloc((size_t)E2CAP * 8);
    size_t o_h1   = alloc((size_t)F1CAP * CH * 4);  // fallback if nf1 > HCAP
    (void)ws_size;

    Params p;
    p.x    = x;
    p.src  = ei;
    p.dst  = ei + E;
    p.np_  = np_;
    p.W1   = (const float*)d_in[3];
    p.b1   = (const float*)d_in[4];
    p.W2   = (const float*)d_in[5];
    p.b2   = (const float*)d_in[6];
    p.fcW  = (const float*)d_in[7];
    p.fcb  = (const float*)d_in[8];
    p.bar   = (int*)(w + o_bar);
    p.ctrl  = (int*)(w + o_ctrl);
    p.bmF1  = (unsigned*)(w + o_bmF1);
    p.bmOut = (unsigned*)(w + o_bmOut);
    p.deg   = (int*)(w + o_deg);
    p.agg1e = (float*)(w + o_agg);
    p.pos1  = (int*)(w + o_pos);
    p.e1sd  = (long long*)(w + o_e1sd);
    p.F1    = (int*)(w + o_F1);
    p.e2sd  = (long long*)(w + o_e2sd);
    p.h1g   = (float*)(w + o_h1);
    p.out  = (float*)d_out;
    p.E = E; p.N = N; p.bmN = bmN;

    (void)hipMemsetAsync(d_ws, 0, zero_end, stream);   // ~1.5 MB

    k_fused<<<GRID, BLK, 0, stream>>>(p);
}

// Round 12
// 122.429 us; speedup vs baseline: 1.0107x; 1.0107x over previous
//
#include <hip/hip_runtime.h>
#include <math.h>

// GCN link predictor, sparse-cone evaluation (round 14 = exact revert to
// round 12, the session best: kernel <42us, bench 122.0us).
// Round-13 post-mortem: block-0 h1 GEMM (64 waves -> 8 waves) + 64KB LDS h1
// mirror regressed the kernel 42 -> 54.5us (VGPR 48->124, LDS 83KB, 250K
// bank conflicts, serialized latency chains). Reverted. Remaining kernel
// structure (~35-40us: ramp + 3 dependent scans + 5 fenceless syncs +
// latency-bound gather + tail) is the algorithm's floor at this size; the
// bench is dominated by ~80us fixed harness overhead (43us poison fill +
// launch slots).
//
// Phases (one plain launch, 5 fenceless flag barriers):
//  P1  scan dst: e1 edges; register F1                       -- B1 --
//  P2  copy bmF1->LDS; scan dst: e2 edges; need-bits src     -- B2 --
//  P3  copy bmNd->LDS; scan dst: deg[d]++ if need-bit       -- B3 --
//  P4  edge-parallel agg incl. self-loop virtual edges       -- B4 --
//      (blocks >= 8 arrive with final flag and exit)
//  P5  per-F1-row GEMM on blocks 0..7                        -- B5 --
//  P6  block 0: layer-2 agg + @W2+b2, relu, fc, sigmoid

#define CH 64
#define E1CAP 4096
#define F1CAP (E1CAP + 2)
#define E2CAP 131072
#define GRID 256
#define BLK 512
#define NWAVE (BLK / 64)
#define NP5 8
#define BMCAP 3200
#define SPIN_MAX (1 << 20)

struct Params {
    const float* x;
    const int* src; const int* dst; const int* np_;
    const float* W1; const float* b1;
    const float* W2; const float* b2;
    const float* fcW; const float* fcb;
    int* bar;          // [16*b] = block b flag (64B stride), monotone
    int* ctrl;         // [0]=cnt_e1 [1]=cnt_e2 [2]=nf1
    int* deg;
    unsigned* bmF1; unsigned* bmNd;
    int* pos1; long long* e1sd; int* F1;
    long long* e2sd; float* h1; float* agg1e;
    float* out;
    int E; int N; int bmN;
};

__device__ __forceinline__ float dinv_of(int degv) {
    return rsqrtf((float)(degv + 1));
}

__device__ __forceinline__ void st_agent(int* p, int v) {
    __hip_atomic_store(p, v, __ATOMIC_RELAXED, __HIP_MEMORY_SCOPE_AGENT);
}
__device__ __forceinline__ void st_agent_f(float* p, float v) {
    __hip_atomic_store(p, v, __ATOMIC_RELAXED, __HIP_MEMORY_SCOPE_AGENT);
}
__device__ __forceinline__ void st_agent64(long long* p, long long v) {
    __hip_atomic_store(p, v, __ATOMIC_RELAXED, __HIP_MEMORY_SCOPE_AGENT);
}
__device__ __forceinline__ int ld_agent(const int* p) {
    return __hip_atomic_load((int*)p, __ATOMIC_RELAXED, __HIP_MEMORY_SCOPE_AGENT);
}
__device__ __forceinline__ long long ld_agent64(const long long* p) {
    return __hip_atomic_load((long long*)p, __ATOMIC_RELAXED, __HIP_MEMORY_SCOPE_AGENT);
}
__device__ __forceinline__ float ld_agent_f(const float* p) {
    return __hip_atomic_load((float*)p, __ATOMIC_RELAXED, __HIP_MEMORY_SCOPE_AGENT);
}

// Fenceless barrier (uncached-mutable discipline; R8-proven).
__device__ __forceinline__ void gbar_arrive(int* bar, int phase) {
    __syncthreads();
    if (threadIdx.x == 0) {
        asm volatile("" ::: "memory");
        st_agent(&bar[blockIdx.x << 4], phase);
    }
}
__device__ __forceinline__ void gbar_wait(int* bar, int phase) {
    if (threadIdx.x < 64) {
        const int l = threadIdx.x;
        for (int it = 0; ; ++it) {
            int a = ld_agent(&bar[l << 4]);
            int b = ld_agent(&bar[(l + 64) << 4]);
            int c = ld_agent(&bar[(l + 128) << 4]);
            int d = ld_agent(&bar[(l + 192) << 4]);
            if (__all(min(min(a, b), min(c, d)) >= phase) || it > SPIN_MAX) break;
            __builtin_amdgcn_s_sleep(1);
        }
    }
    __syncthreads();
}
__device__ __forceinline__ void gbar(int* bar, int phase) {
    gbar_arrive(bar, phase);
    gbar_wait(bar, phase);
}

__device__ __forceinline__ void reg_node(int u, unsigned* bmF1, unsigned* bmNd,
                                         int* ctrl, int* F1, int* pos1) {
    unsigned bit = 1u << (u & 31);
    unsigned old = atomicOr(&bmF1[u >> 5], bit);
    if (!(old & bit)) {
        atomicOr(&bmNd[u >> 5], bit);
        int i = atomicAdd(&ctrl[2], 1);
        st_agent(&F1[i], u);
        st_agent(&pos1[u], i);
    }
}

__device__ __forceinline__ long long pack_sd(int s, int d) {
    return ((long long)(unsigned)d << 32) | (unsigned)s;
}

// P1: batched scan; e1 collection + F1 registration.
__device__ __forceinline__ void phase_e1f1(int gid, int gsz,
                                           const int* __restrict__ src,
                                           const int* __restrict__ dst, int E,
                                           int p0, int p1, int* ctrl,
                                           long long* e1sd,
                                           unsigned* bmF1, unsigned* bmNd,
                                           int* F1, int* pos1) {
    if (gid == 0) {
        reg_node(p0, bmF1, bmNd, ctrl, F1, pos1);
        if (p1 != p0) reg_node(p1, bmF1, bmNd, ctrl, F1, pos1);
    }
    const int nvec = E >> 2;
    const int4* dst4 = (const int4*)dst;
    for (int base = gid; base < nvec; base += gsz * 4) {
        int4 v[4];
#pragma unroll
        for (int t = 0; t < 4; t++) {
            int i = base + t * gsz;
            if (i < nvec) v[t] = dst4[i];
        }
#pragma unroll
        for (int t = 0; t < 4; t++) {
            int i = base + t * gsz;
            if (i >= nvec) continue;
            int ds[4] = {v[t].x, v[t].y, v[t].z, v[t].w};
#pragma unroll
            for (int k = 0; k < 4; k++) {
                int d = ds[k];
                if (d == p0 || d == p1) {
                    int s = src[i * 4 + k];
                    int idx = atomicAdd(&ctrl[0], 1);
                    if (idx < E1CAP) st_agent64(&e1sd[idx], pack_sd(s, d));
                    reg_node(s, bmF1, bmNd, ctrl, F1, pos1);
                }
            }
        }
    }
    for (int e = (nvec << 2) + gid; e < E; e += gsz) {
        int d = dst[e];
        if (d == p0 || d == p1) {
            int s = src[e];
            int idx = atomicAdd(&ctrl[0], 1);
            if (idx < E1CAP) st_agent64(&e1sd[idx], pack_sd(s, d));
            reg_node(s, bmF1, bmNd, ctrl, F1, pos1);
        }
    }
}

// P2: bmF1 -> LDS, then batched scan; per-edge test is an LDS hit.
__device__ __forceinline__ void phase_e2(int tid, int gid, int gsz,
                                         const int* __restrict__ src,
                                         const int* __restrict__ dst, int E,
                                         const unsigned* __restrict__ bmF1,
                                         unsigned* bmNd, int* ctrl,
                                         long long* e2sd,
                                         unsigned* lbm, int bmN) {
    const bool lds_ok = (bmN <= BMCAP);
    if (lds_ok)
        for (int i = tid; i < bmN; i += BLK) lbm[i] = bmF1[i];
    __syncthreads();
    const int nvec = E >> 2;
    const int4* dst4 = (const int4*)dst;
    for (int base = gid; base < nvec; base += gsz * 4) {
        int4 v[4];
#pragma unroll
        for (int t = 0; t < 4; t++) {
            int i = base + t * gsz;
            if (i < nvec) v[t] = dst4[i];
        }
#pragma unroll
        for (int t = 0; t < 4; t++) {
            int i = base + t * gsz;
            if (i >= nvec) continue;
            int ds[4] = {v[t].x, v[t].y, v[t].z, v[t].w};
#pragma unroll
            for (int k = 0; k < 4; k++) {
                int d = ds[k];
                unsigned word;
                if (lds_ok) word = lbm[d >> 5]; else word = bmF1[d >> 5];
                if ((word >> (d & 31)) & 1u) {
                    int s = src[i * 4 + k];
                    atomicOr(&bmNd[s >> 5], 1u << (s & 31));
                    int idx = atomicAdd(&ctrl[1], 1);
                    if (idx < E2CAP) st_agent64(&e2sd[idx], pack_sd(s, d));
                }
            }
        }
    }
    for (int e = (nvec << 2) + gid; e < E; e += gsz) {
        int d = dst[e];
        unsigned word;
        if (lds_ok) word = lbm[d >> 5]; else word = bmF1[d >> 5];
        if ((word >> (d & 31)) & 1u) {
            int s = src[e];
            atomicOr(&bmNd[s >> 5], 1u << (s & 31));
            int idx = atomicAdd(&ctrl[1], 1);
            if (idx < E2CAP) st_agent64(&e2sd[idx], pack_sd(s, d));
        }
    }
}

// P3: bmNd -> LDS, then batched scan; deg count for need-set nodes.
__device__ __forceinline__ void phase_deg(int tid, int gid, int gsz,
                                          const int* __restrict__ dst, int E,
                                          const unsigned* __restrict__ bmNd,
                                          int* deg, unsigned* lbm, int bmN) {
    const bool lds_ok = (bmN <= BMCAP);
    if (lds_ok)
        for (int i = tid; i < bmN; i += BLK) lbm[i] = bmNd[i];
    __syncthreads();
    const int nvec = E >> 2;
    const int4* dst4 = (const int4*)dst;
    for (int base = gid; base < nvec; base += gsz * 4) {
        int4 v[4];
#pragma unroll
        for (int t = 0; t < 4; t++) {
            int i = base + t * gsz;
            if (i < nvec) v[t] = dst4[i];
        }
#pragma unroll
        for (int t = 0; t < 4; t++) {
            int i = base + t * gsz;
            if (i >= nvec) continue;
            int ds[4] = {v[t].x, v[t].y, v[t].z, v[t].w};
#pragma unroll
            for (int k = 0; k < 4; k++) {
                int d = ds[k];
                unsigned word;
                if (lds_ok) word = lbm[d >> 5]; else word = bmNd[d >> 5];
                if ((word >> (d & 31)) & 1u) atomicAdd(&deg[d], 1);
            }
        }
    }
    for (int e = (nvec << 2) + gid; e < E; e += gsz) {
        int d = dst[e];
        unsigned word;
        if (lds_ok) word = lbm[d >> 5]; else word = bmNd[d >> 5];
        if ((word >> (d & 31)) & 1u) atomicAdd(&deg[d], 1);
    }
}

// P4: edge-parallel aggregation incl. self-loop virtual edges (grid-wide:
// the scattered x-row gather needs full-chip TLP - r9/r13 lesson).
__device__ __forceinline__ void phase_agg(int gid, int gsz,
                                          const float* __restrict__ x,
                                          const int* __restrict__ deg,
                                          const int* __restrict__ pos1,
                                          const int* __restrict__ ctrl,
                                          const long long* __restrict__ e2sd,
                                          const int* __restrict__ F1,
                                          float* __restrict__ agg1e) {
    int cnt2 = min(ld_agent(&ctrl[1]), E2CAP);
    int nf1  = min(ld_agent(&ctrl[2]), F1CAP);
    int total = (cnt2 + nf1) << 6;
    for (int idx = gid; idx < total; idx += gsz) {
        int e = idx >> 6, c = idx & 63;
        int row; float val;
        if (e < cnt2) {
            long long sd = ld_agent64(&e2sd[e]);
            int s = (int)(sd & 0xffffffffll), u = (int)(sd >> 32);
            float nrm = dinv_of(ld_agent(&deg[s])) * dinv_of(ld_agent(&deg[u]));
            row = ld_agent(&pos1[u]);
            val = nrm * x[(size_t)s * CH + c];
        } else {
            int i = e - cnt2;
            int u = ld_agent(&F1[i]);
            float du = dinv_of(ld_agent(&deg[u]));
            row = i;
            val = du * du * x[(size_t)u * CH + c];
        }
        atomicAdd(&agg1e[row * CH + c], val);
    }
}

// P5 (blocks 0..NP5-1): one F1 row per wave; h1 = relu(agg1e @ W1 + b1).
__device__ __forceinline__ void phase_h1g(int blockId, int tid,
                                          const float* __restrict__ W1,
                                          const float* __restrict__ b1,
                                          const int* __restrict__ ctrl,
                                          const float* __restrict__ agg1e,
                                          float* __restrict__ h1,
                                          float (*a)[CH]) {
    int nf1 = min(ld_agent(&ctrl[2]), F1CAP);
    int w = tid >> 6, j = tid & 63;
    for (int i = blockId * NWAVE + w; i < nf1; i += NP5 * NWAVE) {
        a[w][j] = ld_agent_f(&agg1e[i * CH + j]);   // same-wave LDS RAW
        float sum = b1[j];
#pragma unroll
        for (int k = 0; k < CH; k++) sum += a[w][k] * W1[k * CH + j];
        st_agent_f(&h1[i * CH + j], fmaxf(sum, 0.f));
    }
}

// P6 (block 0): layer-2 agg (4 waves/endpoint) + @W2+b2, relu, fc, sigmoid.
__device__ __forceinline__ void phase_tail(int tid,
                                           const float* __restrict__ h1,
                                           const int* __restrict__ deg,
                                           const int* __restrict__ pos1,
                                           const int* __restrict__ np_,
                                           const int* __restrict__ ctrl,
                                           const long long* __restrict__ e1sd,
                                           const float* __restrict__ W2,
                                           const float* __restrict__ b2,
                                           const float* __restrict__ fcW,
                                           const float* __restrict__ fcb,
                                           float* __restrict__ out,
                                           float (*a2p)[CH], float (*a2)[CH],
                                           float* partial) {
    int w = tid >> 6, j = tid & 63;
    int t = w >> 2, sub = w & 3;          // 4 waves per endpoint
    int pp = np_[t];
    float dp = dinv_of(ld_agent(&deg[pp]));
    float acc = (sub == 0)
        ? dp * dp * ld_agent_f(&h1[ld_agent(&pos1[pp]) * CH + j]) : 0.f;
    int cnt1 = min(ld_agent(&ctrl[0]), E1CAP);
    for (int e = sub; e < cnt1; e += 4) {
        long long sd = ld_agent64(&e1sd[e]);
        int s = (int)(sd & 0xffffffffll), d = (int)(sd >> 32);
        if (d == pp) {
            acc += dinv_of(ld_agent(&deg[s])) * dp *
                   ld_agent_f(&h1[ld_agent(&pos1[s]) * CH + j]);
        }
    }
    a2p[w][j] = acc;
    __syncthreads();
    if (tid < 128) {
        int t2 = tid >> 6;
        a2[t2][j] = a2p[t2 * 4][j] + a2p[t2 * 4 + 1][j] +
                    a2p[t2 * 4 + 2][j] + a2p[t2 * 4 + 3][j];
    }
    __syncthreads();
    if (tid < 128) {
        int t2 = tid >> 6;
        float sum = b2[j];
#pragma unroll
        for (int k = 0; k < CH; k++) sum += a2[t2][k] * W2[k * CH + j];
        float v = fmaxf(sum, 0.f);
        float pr = v * fcW[t2 * CH + j];
        for (int off = 32; off > 0; off >>= 1) pr += __shfl_down(pr, off);
        if (j == 0) partial[t2] = pr;
    }
    __syncthreads();
    if (tid == 0) {
        float z = partial[0] + partial[1] + fcb[0];
        out[0] = 1.f / (1.f + expf(-z));
    }
}

__global__ __launch_bounds__(BLK, 1) void k_fused(Params p) {
    __shared__ unsigned lbm[BMCAP];     // 12.8 KB bitmap mirror
    __shared__ float a[NWAVE][CH];
    __shared__ float a2p[NWAVE][CH];
    __shared__ float a2[2][CH];
    __shared__ float partial[2];
    const int gid = blockIdx.x * BLK + threadIdx.x;
    const int gsz = GRID * BLK;

    phase_e1f1(gid, gsz, p.src, p.dst, p.E, p.np_[0], p.np_[1], p.ctrl,
               p.e1sd, p.bmF1, p.bmNd, p.F1, p.pos1);
    gbar(p.bar, 1);
    phase_e2(threadIdx.x, gid, gsz, p.src, p.dst, p.E, p.bmF1, p.bmNd,
             p.ctrl, p.e2sd, lbm, p.bmN);
    gbar(p.bar, 2);
    phase_deg(threadIdx.x, gid, gsz, p.dst, p.E, p.bmNd, p.deg, lbm, p.bmN);
    gbar(p.bar, 3);
    phase_agg(gid, gsz, p.x, p.deg, p.pos1, p.ctrl, p.e2sd, p.F1, p.agg1e);
    if (blockIdx.x >= NP5) {          // no P5/P6 duties: final arrival + exit
        gbar_arrive(p.bar, 5);
        return;
    }
    gbar(p.bar, 4);
    phase_h1g(blockIdx.x, threadIdx.x, p.W1, p.b1, p.ctrl, p.agg1e, p.h1, a);
    gbar_arrive(p.bar, 5);
    if (blockIdx.x != 0) return;
    gbar_wait(p.bar, 5);
    phase_tail(threadIdx.x, p.h1, p.deg, p.pos1, p.np_, p.ctrl, p.e1sd,
               p.W2, p.b2, p.fcW, p.fcb, (float*)p.out, a2p, a2, partial);
}

extern "C" void kernel_launch(void* const* d_in, const int* in_sizes, int n_in,
                              void* d_out, int out_size, void* d_ws, size_t ws_size,
                              hipStream_t stream) {
    const float* x   = (const float*)d_in[0];
    const int*   ei  = (const int*)d_in[1];
    const int*   np_ = (const int*)d_in[2];

    const int N = in_sizes[0] / CH;
    const int E = in_sizes[1] / 2;
    const int bmN = (N + 31) / 32;

    char* w = (char*)d_ws;
    size_t off = 0;
    auto alloc = [&](size_t bytes) {
        size_t o = off;
        off = (off + bytes + 255) & ~((size_t)255);
        return o;
    };
    // --- zeroed region (~1.5 MB, fill engine): bar + ctrl + bitmaps + deg
    //     + agg1e ---
    size_t o_bar  = alloc((size_t)GRID * 16 * 4);   // 64B-strided flags
    size_t o_ctrl = alloc(64);                      // cnt_e1, cnt_e2, nf1
    size_t o_bmF1 = alloc((size_t)bmN * 4);
    size_t o_bmNd = alloc((size_t)bmN * 4);
    size_t o_deg  = alloc((size_t)N * 4);
    size_t o_agg  = alloc((size_t)F1CAP * CH * 4);
    size_t zero_end = off;
    // --- uninitialized region ---
    size_t o_pos  = alloc((size_t)N * 4);
    size_t o_e1sd = alloc((size_t)E1CAP * 8);
    size_t o_F1   = alloc((size_t)F1CAP * 4);
    size_t o_e2sd = alloc((size_t)E2CAP * 8);
    size_t o_h1   = alloc((size_t)F1CAP * CH * 4);
    (void)ws_size;

    Params p;
    p.x    = x;
    p.src  = ei;
    p.dst  = ei + E;
    p.np_  = np_;
    p.W1   = (const float*)d_in[3];
    p.b1   = (const float*)d_in[4];
    p.W2   = (const float*)d_in[5];
    p.b2   = (const float*)d_in[6];
    p.fcW  = (const float*)d_in[7];
    p.fcb  = (const float*)d_in[8];
    p.bar   = (int*)(w + o_bar);
    p.ctrl  = (int*)(w + o_ctrl);
    p.bmF1  = (unsigned*)(w + o_bmF1);
    p.bmNd  = (unsigned*)(w + o_bmNd);
    p.deg   = (int*)(w + o_deg);
    p.agg1e = (float*)(w + o_agg);
    p.pos1  = (int*)(w + o_pos);
    p.e1sd  = (long long*)(w + o_e1sd);
    p.F1    = (int*)(w + o_F1);
    p.e2sd  = (long long*)(w + o_e2sd);
    p.h1    = (float*)(w + o_h1);
    p.out  = (float*)d_out;
    p.E = E; p.N = N; p.bmN = bmN;

    (void)hipMemsetAsync(d_ws, 0, zero_end, stream);   // ~1.5 MB

    k_fused<<<GRID, BLK, 0, stream>>>(p);
}